// Round 5
// baseline (521.230 us; speedup 1.0000x reference)
//
#include <hip/hip_runtime.h>

typedef unsigned short u16;
typedef short bf16x8 __attribute__((ext_vector_type(8)));
typedef float f32x4 __attribute__((ext_vector_type(4)));

// Problem constants: B=4, T=4096, D=1024, N=256, L=768, H=16, dh=64, TE=1024
// I/O dtype: float32 (per reference). Internal MFMA compute: bf16.

__device__ __forceinline__ float b2f(u16 u) {
  union { unsigned int u; float f; } x; x.u = ((unsigned int)u) << 16; return x.f;
}
__device__ __forceinline__ u16 f2b(float f) {
  union { float f; unsigned int u; } x; x.f = f;
  unsigned int u = x.u;
  return (u16)((u + 0x7FFFu + ((u >> 16) & 1u)) >> 16);  // RNE
}

// async global->LDS, 16B per lane. LDS dest = wave-uniform base + lane*16.
#define GLOAD_LDS16(g, l)                                                      \
  __builtin_amdgcn_global_load_lds(                                            \
      (const __attribute__((address_space(1))) unsigned int*)(g),              \
      (__attribute__((address_space(3))) unsigned int*)(l), 16, 0, 0)

// ---------------------------------------------------------------------------
// Fused 4-way transpose + f32->bf16: dst[C][R] = bf16(src[R][C]), C=1024.
// grid (32, 32, 4), block (32,8). z selects {Wq,Wk,Wv,Wo}; R in {1024,768}.
// ---------------------------------------------------------------------------
__global__ __launch_bounds__(256) void transpose4_k(
    const float* __restrict__ Wq, const float* __restrict__ Wk,
    const float* __restrict__ Wv, const float* __restrict__ Wo,
    u16* __restrict__ wqt, u16* __restrict__ wkt,
    u16* __restrict__ wvt, u16* __restrict__ wot) {
  const float* src; u16* dst; int R;
  switch (blockIdx.z) {
    case 0: src = Wq; dst = wqt; R = 1024; break;
    case 1: src = Wk; dst = wkt; R = 768;  break;
    case 2: src = Wv; dst = wvt; R = 768;  break;
    default: src = Wo; dst = wot; R = 1024; break;
  }
  int bx = blockIdx.x * 32, by = blockIdx.y * 32;
  if (by >= R) return;
  __shared__ float t[32][33];
  int x = threadIdx.x, y = threadIdx.y;
#pragma unroll
  for (int i = 0; i < 4; ++i)
    t[y * 4 + i][x] = src[(size_t)(by + y * 4 + i) * 1024 + bx + x];
  __syncthreads();
#pragma unroll
  for (int i = 0; i < 4; ++i)
    dst[(size_t)(bx + y * 4 + i) * R + by + x] = f2b(t[x][y * 4 + i]);
}

// ---------------------------------------------------------------------------
// Row LayerNorm, f32 in -> bf16 out. One block per row. C in {768, 1024}.
// ---------------------------------------------------------------------------
__global__ __launch_bounds__(256) void ln_k(const float* __restrict__ in,
                                            const float* __restrict__ g,
                                            const float* __restrict__ bta,
                                            u16* __restrict__ out, int C) {
  int row = blockIdx.x, tid = threadIdx.x;
  const float* p = in + (size_t)row * C;
  int i0 = tid * 4;
  bool act = i0 < C;
  float v0 = 0.f, v1 = 0.f, v2 = 0.f, v3 = 0.f;
  if (act) {
    float4 u = *(const float4*)(p + i0);
    v0 = u.x; v1 = u.y; v2 = u.z; v3 = u.w;
  }
  float s = v0 + v1 + v2 + v3;
  float q = v0 * v0 + v1 * v1 + v2 * v2 + v3 * v3;
  __shared__ float red[8];
#pragma unroll
  for (int m = 32; m; m >>= 1) { s += __shfl_xor(s, m); q += __shfl_xor(q, m); }
  if ((tid & 63) == 0) { red[tid >> 6] = s; red[4 + (tid >> 6)] = q; }
  __syncthreads();
  s = red[0] + red[1] + red[2] + red[3];
  q = red[4] + red[5] + red[6] + red[7];
  float invC = 1.0f / (float)C;
  float mu = s * invC;
  float rs = rsqrtf(q * invC - mu * mu + 1e-5f);
  if (act) {
    float4 ug = *(const float4*)(g + i0);
    float4 ub = *(const float4*)(bta + i0);
    ushort4 o;
    o.x = f2b((v0 - mu) * rs * ug.x + ub.x);
    o.y = f2b((v1 - mu) * rs * ug.y + ub.y);
    o.z = f2b((v2 - mu) * rs * ug.z + ub.z);
    o.w = f2b((v3 - mu) * rs * ug.w + ub.w);
    *(ushort4*)(out + (size_t)row * C + i0) = o;
  }
}

// ---------------------------------------------------------------------------
// Stylization (in-place safe): out = bf16( silu( LN(y)*(1+scale_b) + shift_b ) ).
// ---------------------------------------------------------------------------
__global__ __launch_bounds__(256) void style_k(const u16* __restrict__ y,
                                               const float* __restrict__ g,
                                               const float* __restrict__ bta,
                                               const float* __restrict__ embo,
                                               u16* __restrict__ out) {
  int row = blockIdx.x, tid = threadIdx.x;
  int b = row >> 12;  // T=4096
  const u16* p = y + (size_t)row * 1024;
  int i0 = tid * 4;
  ushort4 u = *(const ushort4*)(p + i0);
  float v0 = b2f(u.x), v1 = b2f(u.y), v2 = b2f(u.z), v3 = b2f(u.w);
  float s = v0 + v1 + v2 + v3;
  float q = v0 * v0 + v1 * v1 + v2 * v2 + v3 * v3;
  __shared__ float red[8];
#pragma unroll
  for (int m = 32; m; m >>= 1) { s += __shfl_xor(s, m); q += __shfl_xor(q, m); }
  if ((tid & 63) == 0) { red[tid >> 6] = s; red[4 + (tid >> 6)] = q; }
  __syncthreads();
  s = red[0] + red[1] + red[2] + red[3];
  q = red[4] + red[5] + red[6] + red[7];
  const float invC = 1.0f / 1024.0f;
  float mu = s * invC;
  float rs = rsqrtf(q * invC - mu * mu + 1e-5f);
  float4 ug = *(const float4*)(g + i0);
  float4 ub = *(const float4*)(bta + i0);
  float4 sc = *(const float4*)(embo + b * 2048 + i0);
  float4 sh = *(const float4*)(embo + b * 2048 + 1024 + i0);
  float h0 = ((v0 - mu) * rs * ug.x + ub.x) * (1.0f + sc.x) + sh.x;
  float h1 = ((v1 - mu) * rs * ug.y + ub.y) * (1.0f + sc.y) + sh.y;
  float h2 = ((v2 - mu) * rs * ug.z + ub.z) * (1.0f + sc.z) + sh.z;
  float h3 = ((v3 - mu) * rs * ug.w + ub.w) * (1.0f + sc.w) + sh.w;
  ushort4 o;
  o.x = f2b(h0 / (1.0f + __expf(-h0)));
  o.y = f2b(h1 / (1.0f + __expf(-h1)));
  o.z = f2b(h2 / (1.0f + __expf(-h2)));
  o.w = f2b(h3 / (1.0f + __expf(-h3)));
  *(ushort4*)(out + (size_t)row * 1024 + i0) = o;
}

// ---------------------------------------------------------------------------
// emb_out[b][j] = sum_i silu(emb[b][i]) * We[i][j] + be[j], all f32.
// ---------------------------------------------------------------------------
__global__ __launch_bounds__(256) void emb_k(const float* __restrict__ emb,
                                             const float* __restrict__ We,
                                             const float* __restrict__ be,
                                             float* __restrict__ embo) {
  int b = blockIdx.y, tid = threadIdx.x;
  int j = blockIdx.x * 256 + tid;
  __shared__ float se[1024];
  for (int i = tid; i < 1024; i += 256) {
    float v = emb[b * 1024 + i];
    se[i] = v / (1.0f + __expf(-v));
  }
  __syncthreads();
  float acc = 0.f;
#pragma unroll 8
  for (int i = 0; i < 1024; ++i) acc += se[i] * We[(size_t)i * 2048 + j];
  embo[b * 2048 + j] = acc + be[j];
}

// ---------------------------------------------------------------------------
// GEMM  C[M][Nn] = A[M][K] @ Bt[Nn][K]^T + bias(f32), A/Bt bf16.
// m97 structure + XCD-aware mapping: ROW blocks on blockIdx.x so that the
// column-blocks sharing one A row-strip land on the SAME XCD (linear%8 ==
// rowblk%8) and share its L2 copy of A — kills the ~6x A re-fetch seen in r4.
// mode 0: Cb[row*Nn+col] (bf16)
// mode 1: V-transpose store: Cb[((row>>8)*1024 + col)*256 + (row&255)] (bf16)
// mode 2: Cf[row*Nn+col] = acc + bias + res[row*Nn+col]  (f32 out, f32 res)
// ---------------------------------------------------------------------------
__global__ __launch_bounds__(256) void gemm_bt_k(const u16* __restrict__ A,
                                                 const u16* __restrict__ Bt,
                                                 const float* __restrict__ bias,
                                                 const float* __restrict__ res,
                                                 u16* __restrict__ Cb,
                                                 float* __restrict__ Cf,
                                                 int M, int Nn, int K, int mode) {
  __shared__ __align__(16) short As[128 * 64];
  __shared__ __align__(16) short Bs[128 * 64];
  int tid = threadIdx.x;
  int m0 = blockIdx.x * 128, n0 = blockIdx.y * 128;  // rows on x (XCD swizzle)
  int wave = tid >> 6, lane = tid & 63;
  int l16 = lane & 15, quad = lane >> 4;
  int wm = (wave >> 1) * 64, wn = (wave & 1) * 64;

  f32x4 acc[4][4];
#pragma unroll
  for (int i = 0; i < 4; ++i)
#pragma unroll
    for (int j = 0; j < 4; ++j)
#pragma unroll
      for (int r = 0; r < 4; ++r) acc[i][j][r] = 0.f;

  for (int kt = 0; kt < K; kt += 64) {
    // 1024 16B-chunks per operand; chunk c -> row c>>3, col (c&7)*8 shorts.
    // LDS offset of chunk c = c*8 shorts (row-major, stride 64, no padding —
    // required by global_load_lds's wave-uniform-base + lane*16 semantics).
#pragma unroll
    for (int p = 0; p < 4; ++p) {
      int c = p * 256 + tid;
      int r = c >> 3, cd = (c & 7) * 8;
      int lb = (p * 256 + wave * 64) * 8;  // wave's LDS chunk base (shorts)
      GLOAD_LDS16(A + (size_t)(m0 + r) * K + kt + cd, As + lb);
      GLOAD_LDS16(Bt + (size_t)(n0 + r) * K + kt + cd, Bs + lb);
    }
    __syncthreads();
#pragma unroll
    for (int ks = 0; ks < 2; ++ks) {
      bf16x8 af[4], bfr[4];
#pragma unroll
      for (int i = 0; i < 4; ++i)
        af[i] = *(const bf16x8*)&As[(wm + i * 16 + l16) * 64 + ks * 32 + quad * 8];
#pragma unroll
      for (int j = 0; j < 4; ++j)
        bfr[j] = *(const bf16x8*)&Bs[(wn + j * 16 + l16) * 64 + ks * 32 + quad * 8];
#pragma unroll
      for (int i = 0; i < 4; ++i)
#pragma unroll
        for (int j = 0; j < 4; ++j)
          acc[i][j] = __builtin_amdgcn_mfma_f32_16x16x32_bf16(af[i], bfr[j], acc[i][j], 0, 0, 0);
    }
    __syncthreads();
  }

#pragma unroll
  for (int j = 0; j < 4; ++j) {
    int col = n0 + wn + j * 16 + l16;
    float bv = bias[col];
#pragma unroll
    for (int i = 0; i < 4; ++i) {
      int row0 = m0 + wm + i * 16 + quad * 4;
#pragma unroll
      for (int r = 0; r < 4; ++r) {
        int row = row0 + r;
        float v = acc[i][j][r] + bv;
        if (mode == 2) {
          Cf[(size_t)row * Nn + col] = v + res[(size_t)row * Nn + col];
        } else if (mode == 1) {
          Cb[((size_t)((row >> 8) * 1024 + col)) * 256 + (row & 255)] = f2b(v);
        } else {
          Cb[(size_t)row * Nn + col] = f2b(v);
        }
      }
    }
  }
}

// ---------------------------------------------------------------------------
// Cross-attention: per (b,h), 64 Q-rows per block (4 waves x 16 rows).
// All operands bf16, accum f32. LDS = exactly 64 KB.
// ---------------------------------------------------------------------------
__global__ __launch_bounds__(256) void attn_k(const u16* __restrict__ Q,
                                              const u16* __restrict__ Kt,
                                              const u16* __restrict__ VT,
                                              u16* __restrict__ Y) {
  __shared__ __align__(16) short KsPs[256 * 64];  // K tile; reused as P (64x256)
  __shared__ __align__(16) short Vt[64 * 256];    // V^T tile: [d][token]
  int tid = threadIdx.x;
  int t0 = blockIdx.x * 64, h = blockIdx.y, b = blockIdx.z;
  int wave = tid >> 6, lane = tid & 63;
  int l16 = lane & 15, quad = lane >> 4;
  int wb = wave * 16;

#pragma unroll
  for (int p = 0; p < 8; ++p) {
    int c = tid + p * 256;
    int n = c >> 3, cd = c & 7;
    *(int4*)&KsPs[n * 64 + ((cd ^ (n & 7)) * 8)] =
        *(const int4*)(Kt + ((size_t)(b * 256 + n)) * 1024 + h * 64 + cd * 8);
  }
#pragma unroll
  for (int p = 0; p < 8; ++p) {
    int c = tid + p * 256;
    int d = c >> 5, ch = c & 31;
    *(int4*)&Vt[d * 256 + ((ch ^ (d & 7)) * 8)] =
        *(const int4*)(VT + ((size_t)(b * 1024 + h * 64 + d)) * 256 + ch * 8);
  }
  const u16* qrow = Q + ((size_t)(b * 4096 + t0 + wb + l16)) * 1024 + h * 64;
  bf16x8 qf0 = *(const bf16x8*)(qrow + quad * 8);
  bf16x8 qf1 = *(const bf16x8*)(qrow + 32 + quad * 8);
  __syncthreads();

  f32x4 sa[16];
#pragma unroll
  for (int nt = 0; nt < 16; ++nt)
#pragma unroll
    for (int r = 0; r < 4; ++r) sa[nt][r] = 0.f;
#pragma unroll
  for (int ks = 0; ks < 2; ++ks) {
    bf16x8 af = ks ? qf1 : qf0;
#pragma unroll
    for (int nt = 0; nt < 16; ++nt) {
      int n = nt * 16 + l16;
      bf16x8 bfr = *(const bf16x8*)&KsPs[n * 64 + (((ks * 4 + quad) ^ (n & 7)) * 8)];
      sa[nt] = __builtin_amdgcn_mfma_f32_16x16x32_bf16(af, bfr, sa[nt], 0, 0, 0);
    }
  }
  __syncthreads();  // all waves done reading K before P overwrites it

#pragma unroll
  for (int r = 0; r < 4; ++r) {
    float mx = -3.0e38f;
#pragma unroll
    for (int nt = 0; nt < 16; ++nt) mx = fmaxf(mx, sa[nt][r]);
    mx = fmaxf(mx, __shfl_xor(mx, 1));
    mx = fmaxf(mx, __shfl_xor(mx, 2));
    mx = fmaxf(mx, __shfl_xor(mx, 4));
    mx = fmaxf(mx, __shfl_xor(mx, 8));
    float e[16];
    float sum = 0.f;
#pragma unroll
    for (int nt = 0; nt < 16; ++nt) {
      e[nt] = __expf((sa[nt][r] - mx) * 0.125f);
      sum += e[nt];
    }
    sum += __shfl_xor(sum, 1);
    sum += __shfl_xor(sum, 2);
    sum += __shfl_xor(sum, 4);
    sum += __shfl_xor(sum, 8);
    float rsc = 1.0f / sum;
    int prow = wb + quad * 4 + r;
#pragma unroll
    for (int nt = 0; nt < 16; ++nt) {
      int col = nt * 16 + l16;
      KsPs[prow * 256 + (((col >> 3) ^ (prow & 7)) * 8) + (col & 7)] =
          (short)f2b(e[nt] * rsc);
    }
  }
  __syncthreads();

  f32x4 ya[4];
#pragma unroll
  for (int j = 0; j < 4; ++j)
#pragma unroll
    for (int r = 0; r < 4; ++r) ya[j][r] = 0.f;
  int m = wb + l16;
#pragma unroll
  for (int kk = 0; kk < 8; ++kk) {
    bf16x8 af = *(const bf16x8*)&KsPs[m * 256 + (((kk * 4 + quad) ^ (m & 7)) * 8)];
#pragma unroll
    for (int j = 0; j < 4; ++j) {
      int d = j * 16 + l16;
      bf16x8 bfr = *(const bf16x8*)&Vt[d * 256 + (((kk * 4 + quad) ^ (d & 7)) * 8)];
      ya[j] = __builtin_amdgcn_mfma_f32_16x16x32_bf16(af, bfr, ya[j], 0, 0, 0);
    }
  }
#pragma unroll
  for (int j = 0; j < 4; ++j)
#pragma unroll
    for (int r = 0; r < 4; ++r)
      Y[((size_t)(b * 4096 + t0 + wb + quad * 4 + r)) * 1024 + h * 64 + j * 16 + l16] =
          f2b(ya[j][r]);
}

// ---------------------------------------------------------------------------
extern "C" void kernel_launch(void* const* d_in, const int* in_sizes, int n_in,
                              void* d_out, int out_size, void* d_ws, size_t ws_size,
                              hipStream_t stream) {
  const float* x       = (const float*)d_in[0];
  const float* xf      = (const float*)d_in[1];
  const float* emb     = (const float*)d_in[2];
  const float* norm_g  = (const float*)d_in[3];
  const float* norm_b  = (const float*)d_in[4];
  const float* tnorm_g = (const float*)d_in[5];
  const float* tnorm_b = (const float*)d_in[6];
  const float* Wq      = (const float*)d_in[7];
  const float* bq      = (const float*)d_in[8];
  const float* Wk      = (const float*)d_in[9];
  const float* bk      = (const float*)d_in[10];
  const float* Wv      = (const float*)d_in[11];
  const float* bv      = (const float*)d_in[12];
  const float* We      = (const float*)d_in[13];
  const float* be      = (const float*)d_in[14];
  const float* snorm_g = (const float*)d_in[15];
  const float* snorm_b = (const float*)d_in[16];
  const float* Wo      = (const float*)d_in[17];
  const float* bo      = (const float*)d_in[18];

  const size_t MB = 1024 * 1024;
  // d_out (64 MB f32) hosts transient bf16 buffers that die before the final
  // full-d_out write: Q (32 MB) + Wq^T/Wk^T/Wv^T transposed weights.
  char* dout = (char*)d_out;
  u16* qbuf = (u16*)(dout);             // 32 MB bf16 Q (dead after attn)
  u16* wqt  = (u16*)(dout + 32 * MB);   // 2 MB   (dead after Q-GEMM)
  u16* wkt  = (u16*)(dout + 34 * MB);   // 1.5 MB (dead after K-GEMM)
  u16* wvt  = (u16*)(dout + 36 * MB);   // 1.5 MB (dead after V-GEMM)
  float* out = (float*)d_out;

  // Workspace: ~39.6 MB total.
  char* ws = (char*)d_ws;
  u16* big1 = (u16*)(ws);                        // 32 MB: LN(x) -> y -> s
  u16* xfn  = (u16*)(ws + 32 * MB);              // 1.5 MB
  u16* kws  = (u16*)(ws + 33 * MB + 512 * 1024); // 2 MB  (B,256,1024)
  u16* vtws = (u16*)(ws + 35 * MB + 512 * 1024); // 2 MB  (B,1024,256)
  u16* wot  = (u16*)(ws + 37 * MB + 512 * 1024); // 2 MB  (needed during final GEMM)
  float* embo = (float*)(ws + 39 * MB + 512 * 1024); // 32 KB f32

  // weight transposes (f32 -> bf16, B-operand wants k-contiguous), one launch
  transpose4_k<<<dim3(32, 32, 4), dim3(32, 8), 0, stream>>>(
      Wq, Wk, Wv, Wo, wqt, wkt, wvt, wot);

  // layernorms (f32 -> bf16)
  ln_k<<<16384, 256, 0, stream>>>(x, norm_g, norm_b, big1, 1024);
  ln_k<<<1024, 256, 0, stream>>>(xf, tnorm_g, tnorm_b, xfn, 768);

  // projections: Q -> d_out (bf16); K -> kws; V -> vtws (transposed store)
  // rows on grid-x for XCD-local A reuse
  gemm_bt_k<<<dim3(128, 8), 256, 0, stream>>>(big1, wqt, bq, nullptr, qbuf, nullptr, 16384, 1024, 1024, 0);
  gemm_bt_k<<<dim3(8, 8), 256, 0, stream>>>(xfn, wkt, bk, nullptr, kws, nullptr, 1024, 1024, 768, 0);
  gemm_bt_k<<<dim3(8, 8), 256, 0, stream>>>(xfn, wvt, bv, nullptr, vtws, nullptr, 1024, 1024, 768, 1);

  // emb -> scale/shift (f32)
  emb_k<<<dim3(8, 4), 256, 0, stream>>>(emb, We, be, embo);

  // attention: reads Q (=d_out lower half), writes y (bf16) -> big1
  attn_k<<<dim3(64, 16, 4), 256, 0, stream>>>(qbuf, kws, vtws, big1);

  // stylization in-place: big1 (y) -> big1 (s)
  style_k<<<16384, 256, 0, stream>>>(big1, snorm_g, snorm_b, embo, big1);

  // out projection + bias + residual(x, f32) -> d_out (f32, full overwrite)
  gemm_bt_k<<<dim3(128, 8), 256, 0, stream>>>(big1, wot, bo, x, nullptr, out, 16384, 1024, 1024, 2);
}

// Round 6
// 501.517 us; speedup vs baseline: 1.0393x; 1.0393x over previous
//
#include <hip/hip_runtime.h>

typedef unsigned short u16;
typedef short bf16x8 __attribute__((ext_vector_type(8)));
typedef float f32x4 __attribute__((ext_vector_type(4)));

// Problem constants: B=4, T=4096, D=1024, N=256, L=768, H=16, dh=64, TE=1024
// I/O dtype: float32 (per reference). Internal MFMA compute: bf16.

__device__ __forceinline__ float b2f(u16 u) {
  union { unsigned int u; float f; } x; x.u = ((unsigned int)u) << 16; return x.f;
}
__device__ __forceinline__ u16 f2b(float f) {
  union { float f; unsigned int u; } x; x.f = f;
  unsigned int u = x.u;
  return (u16)((u + 0x7FFFu + ((u >> 16) & 1u)) >> 16);  // RNE
}

// async global->LDS, 16B per lane. LDS dest = wave-uniform base + lane*16.
#define GLOAD_LDS16(g, l)                                                      \
  __builtin_amdgcn_global_load_lds(                                            \
      (const __attribute__((address_space(1))) unsigned int*)(g),              \
      (__attribute__((address_space(3))) unsigned int*)(l), 16, 0, 0)

// ---------------------------------------------------------------------------
// Fused 4-way transpose + f32->bf16: dst[C][R] = bf16(src[R][C]), C=1024.
// grid (32, 32, 4), block (32,8). z selects {Wq,Wk,Wv,Wo}; R in {1024,768}.
// ---------------------------------------------------------------------------
__global__ __launch_bounds__(256) void transpose4_k(
    const float* __restrict__ Wq, const float* __restrict__ Wk,
    const float* __restrict__ Wv, const float* __restrict__ Wo,
    u16* __restrict__ wqt, u16* __restrict__ wkt,
    u16* __restrict__ wvt, u16* __restrict__ wot) {
  const float* src; u16* dst; int R;
  switch (blockIdx.z) {
    case 0: src = Wq; dst = wqt; R = 1024; break;
    case 1: src = Wk; dst = wkt; R = 768;  break;
    case 2: src = Wv; dst = wvt; R = 768;  break;
    default: src = Wo; dst = wot; R = 1024; break;
  }
  int bx = blockIdx.x * 32, by = blockIdx.y * 32;
  if (by >= R) return;
  __shared__ float t[32][33];
  int x = threadIdx.x, y = threadIdx.y;
#pragma unroll
  for (int i = 0; i < 4; ++i)
    t[y * 4 + i][x] = src[(size_t)(by + y * 4 + i) * 1024 + bx + x];
  __syncthreads();
#pragma unroll
  for (int i = 0; i < 4; ++i)
    dst[(size_t)(bx + y * 4 + i) * R + by + x] = f2b(t[x][y * 4 + i]);
}

// ---------------------------------------------------------------------------
// Row LayerNorm, f32 in -> bf16 out. One block per row. C in {768, 1024}.
// ---------------------------------------------------------------------------
__global__ __launch_bounds__(256) void ln_k(const float* __restrict__ in,
                                            const float* __restrict__ g,
                                            const float* __restrict__ bta,
                                            u16* __restrict__ out, int C) {
  int row = blockIdx.x, tid = threadIdx.x;
  const float* p = in + (size_t)row * C;
  int i0 = tid * 4;
  bool act = i0 < C;
  float v0 = 0.f, v1 = 0.f, v2 = 0.f, v3 = 0.f;
  if (act) {
    float4 u = *(const float4*)(p + i0);
    v0 = u.x; v1 = u.y; v2 = u.z; v3 = u.w;
  }
  float s = v0 + v1 + v2 + v3;
  float q = v0 * v0 + v1 * v1 + v2 * v2 + v3 * v3;
  __shared__ float red[8];
#pragma unroll
  for (int m = 32; m; m >>= 1) { s += __shfl_xor(s, m); q += __shfl_xor(q, m); }
  if ((tid & 63) == 0) { red[tid >> 6] = s; red[4 + (tid >> 6)] = q; }
  __syncthreads();
  s = red[0] + red[1] + red[2] + red[3];
  q = red[4] + red[5] + red[6] + red[7];
  float invC = 1.0f / (float)C;
  float mu = s * invC;
  float rs = rsqrtf(q * invC - mu * mu + 1e-5f);
  if (act) {
    float4 ug = *(const float4*)(g + i0);
    float4 ub = *(const float4*)(bta + i0);
    ushort4 o;
    o.x = f2b((v0 - mu) * rs * ug.x + ub.x);
    o.y = f2b((v1 - mu) * rs * ug.y + ub.y);
    o.z = f2b((v2 - mu) * rs * ug.z + ub.z);
    o.w = f2b((v3 - mu) * rs * ug.w + ub.w);
    *(ushort4*)(out + (size_t)row * C + i0) = o;
  }
}

// ---------------------------------------------------------------------------
// Stylization (in-place safe): out = bf16( silu( LN(y)*(1+scale_b) + shift_b ) ).
// ---------------------------------------------------------------------------
__global__ __launch_bounds__(256) void style_k(const u16* __restrict__ y,
                                               const float* __restrict__ g,
                                               const float* __restrict__ bta,
                                               const float* __restrict__ embo,
                                               u16* __restrict__ out) {
  int row = blockIdx.x, tid = threadIdx.x;
  int b = row >> 12;  // T=4096
  const u16* p = y + (size_t)row * 1024;
  int i0 = tid * 4;
  ushort4 u = *(const ushort4*)(p + i0);
  float v0 = b2f(u.x), v1 = b2f(u.y), v2 = b2f(u.z), v3 = b2f(u.w);
  float s = v0 + v1 + v2 + v3;
  float q = v0 * v0 + v1 * v1 + v2 * v2 + v3 * v3;
  __shared__ float red[8];
#pragma unroll
  for (int m = 32; m; m >>= 1) { s += __shfl_xor(s, m); q += __shfl_xor(q, m); }
  if ((tid & 63) == 0) { red[tid >> 6] = s; red[4 + (tid >> 6)] = q; }
  __syncthreads();
  s = red[0] + red[1] + red[2] + red[3];
  q = red[4] + red[5] + red[6] + red[7];
  const float invC = 1.0f / 1024.0f;
  float mu = s * invC;
  float rs = rsqrtf(q * invC - mu * mu + 1e-5f);
  float4 ug = *(const float4*)(g + i0);
  float4 ub = *(const float4*)(bta + i0);
  float4 sc = *(const float4*)(embo + b * 2048 + i0);
  float4 sh = *(const float4*)(embo + b * 2048 + 1024 + i0);
  float h0 = ((v0 - mu) * rs * ug.x + ub.x) * (1.0f + sc.x) + sh.x;
  float h1 = ((v1 - mu) * rs * ug.y + ub.y) * (1.0f + sc.y) + sh.y;
  float h2 = ((v2 - mu) * rs * ug.z + ub.z) * (1.0f + sc.z) + sh.z;
  float h3 = ((v3 - mu) * rs * ug.w + ub.w) * (1.0f + sc.w) + sh.w;
  ushort4 o;
  o.x = f2b(h0 / (1.0f + __expf(-h0)));
  o.y = f2b(h1 / (1.0f + __expf(-h1)));
  o.z = f2b(h2 / (1.0f + __expf(-h2)));
  o.w = f2b(h3 / (1.0f + __expf(-h3)));
  *(ushort4*)(out + (size_t)row * 1024 + i0) = o;
}

// ---------------------------------------------------------------------------
// emb_out[b][j] = sum_i silu(emb[b][i]) * We[i][j] + be[j], all f32.
// ---------------------------------------------------------------------------
__global__ __launch_bounds__(256) void emb_k(const float* __restrict__ emb,
                                             const float* __restrict__ We,
                                             const float* __restrict__ be,
                                             float* __restrict__ embo) {
  int b = blockIdx.y, tid = threadIdx.x;
  int j = blockIdx.x * 256 + tid;
  __shared__ float se[1024];
  for (int i = tid; i < 1024; i += 256) {
    float v = emb[b * 1024 + i];
    se[i] = v / (1.0f + __expf(-v));
  }
  __syncthreads();
  float acc = 0.f;
#pragma unroll 8
  for (int i = 0; i < 1024; ++i) acc += se[i] * We[(size_t)i * 2048 + j];
  embo[b * 2048 + j] = acc + be[j];
}

// ---------------------------------------------------------------------------
// GEMM  C[M][Nn] = A[M][K] @ Bt[Nn][K]^T + bias(f32), A/Bt bf16.
// m97 structure + XCD row-mapping + XOR bank swizzle:
//  - global_load_lds writes are contiguous (HW constraint), but each lane's
//    GLOBAL source chunk is swizzled: slot (r, cd) holds global chunk
//    (r, cd ^ (r&7)). Fragment reads xor back. This spreads the former
//    16-way ds_read_b128 bank conflict (row-stride 128B) to 2-way (free).
// mode 0: Cb[row*Nn+col] (bf16)
// mode 1: V-transpose store: Cb[((row>>8)*1024 + col)*256 + (row&255)] (bf16)
// mode 2: Cf[row*Nn+col] = acc + bias + res[row*Nn+col]  (f32 out, f32 res)
// ---------------------------------------------------------------------------
__global__ __launch_bounds__(256) void gemm_bt_k(const u16* __restrict__ A,
                                                 const u16* __restrict__ Bt,
                                                 const float* __restrict__ bias,
                                                 const float* __restrict__ res,
                                                 u16* __restrict__ Cb,
                                                 float* __restrict__ Cf,
                                                 int M, int Nn, int K, int mode) {
  __shared__ __align__(16) short As[128 * 64];
  __shared__ __align__(16) short Bs[128 * 64];
  int tid = threadIdx.x;
  int m0 = blockIdx.x * 128, n0 = blockIdx.y * 128;  // rows on x (XCD swizzle)
  int wave = tid >> 6, lane = tid & 63;
  int l16 = lane & 15, quad = lane >> 4;
  int wm = (wave >> 1) * 64, wn = (wave & 1) * 64;

  f32x4 acc[4][4];
#pragma unroll
  for (int i = 0; i < 4; ++i)
#pragma unroll
    for (int j = 0; j < 4; ++j)
#pragma unroll
      for (int r = 0; r < 4; ++r) acc[i][j][r] = 0.f;

  for (int kt = 0; kt < K; kt += 64) {
    // 1024 16B-chunks per operand; LDS slot c (row c>>3, col c&7) receives
    // global chunk (row, (c&7) ^ (row&7)) — bank swizzle with contiguous
    // LDS writes (required by global_load_lds).
#pragma unroll
    for (int p = 0; p < 4; ++p) {
      int c = p * 256 + tid;
      int r = c >> 3;
      int cd = ((c & 7) ^ (r & 7)) * 8;   // swizzled global column (shorts)
      int lb = (p * 256 + wave * 64) * 8; // wave's LDS chunk base (shorts)
      GLOAD_LDS16(A + (size_t)(m0 + r) * K + kt + cd, As + lb);
      GLOAD_LDS16(Bt + (size_t)(n0 + r) * K + kt + cd, Bs + lb);
    }
    __syncthreads();
#pragma unroll
    for (int ks = 0; ks < 2; ++ks) {
      // fragment rows are wm/wn + i*16 + l16 -> row&7 == l16&7 for all i,j
      int swz = ((ks * 4 + quad) ^ (l16 & 7)) * 8;
      bf16x8 af[4], bfr[4];
#pragma unroll
      for (int i = 0; i < 4; ++i)
        af[i] = *(const bf16x8*)&As[(wm + i * 16 + l16) * 64 + swz];
#pragma unroll
      for (int j = 0; j < 4; ++j)
        bfr[j] = *(const bf16x8*)&Bs[(wn + j * 16 + l16) * 64 + swz];
#pragma unroll
      for (int i = 0; i < 4; ++i)
#pragma unroll
        for (int j = 0; j < 4; ++j)
          acc[i][j] = __builtin_amdgcn_mfma_f32_16x16x32_bf16(af[i], bfr[j], acc[i][j], 0, 0, 0);
    }
    __syncthreads();
  }

#pragma unroll
  for (int j = 0; j < 4; ++j) {
    int col = n0 + wn + j * 16 + l16;
    float bv = bias[col];
#pragma unroll
    for (int i = 0; i < 4; ++i) {
      int row0 = m0 + wm + i * 16 + quad * 4;
#pragma unroll
      for (int r = 0; r < 4; ++r) {
        int row = row0 + r;
        float v = acc[i][j][r] + bv;
        if (mode == 2) {
          Cf[(size_t)row * Nn + col] = v + res[(size_t)row * Nn + col];
        } else if (mode == 1) {
          Cb[((size_t)((row >> 8) * 1024 + col)) * 256 + (row & 255)] = f2b(v);
        } else {
          Cb[(size_t)row * Nn + col] = f2b(v);
        }
      }
    }
  }
}

// ---------------------------------------------------------------------------
// Cross-attention: per (b,h), 64 Q-rows per block (4 waves x 16 rows).
// All operands bf16, accum f32. LDS = exactly 64 KB.
// ---------------------------------------------------------------------------
__global__ __launch_bounds__(256) void attn_k(const u16* __restrict__ Q,
                                              const u16* __restrict__ Kt,
                                              const u16* __restrict__ VT,
                                              u16* __restrict__ Y) {
  __shared__ __align__(16) short KsPs[256 * 64];  // K tile; reused as P (64x256)
  __shared__ __align__(16) short Vt[64 * 256];    // V^T tile: [d][token]
  int tid = threadIdx.x;
  int t0 = blockIdx.x * 64, h = blockIdx.y, b = blockIdx.z;
  int wave = tid >> 6, lane = tid & 63;
  int l16 = lane & 15, quad = lane >> 4;
  int wb = wave * 16;

#pragma unroll
  for (int p = 0; p < 8; ++p) {
    int c = tid + p * 256;
    int n = c >> 3, cd = c & 7;
    *(int4*)&KsPs[n * 64 + ((cd ^ (n & 7)) * 8)] =
        *(const int4*)(Kt + ((size_t)(b * 256 + n)) * 1024 + h * 64 + cd * 8);
  }
#pragma unroll
  for (int p = 0; p < 8; ++p) {
    int c = tid + p * 256;
    int d = c >> 5, ch = c & 31;
    *(int4*)&Vt[d * 256 + ((ch ^ (d & 7)) * 8)] =
        *(const int4*)(VT + ((size_t)(b * 1024 + h * 64 + d)) * 256 + ch * 8);
  }
  const u16* qrow = Q + ((size_t)(b * 4096 + t0 + wb + l16)) * 1024 + h * 64;
  bf16x8 qf0 = *(const bf16x8*)(qrow + quad * 8);
  bf16x8 qf1 = *(const bf16x8*)(qrow + 32 + quad * 8);
  __syncthreads();

  f32x4 sa[16];
#pragma unroll
  for (int nt = 0; nt < 16; ++nt)
#pragma unroll
    for (int r = 0; r < 4; ++r) sa[nt][r] = 0.f;
#pragma unroll
  for (int ks = 0; ks < 2; ++ks) {
    bf16x8 af = ks ? qf1 : qf0;
#pragma unroll
    for (int nt = 0; nt < 16; ++nt) {
      int n = nt * 16 + l16;
      bf16x8 bfr = *(const bf16x8*)&KsPs[n * 64 + (((ks * 4 + quad) ^ (n & 7)) * 8)];
      sa[nt] = __builtin_amdgcn_mfma_f32_16x16x32_bf16(af, bfr, sa[nt], 0, 0, 0);
    }
  }
  __syncthreads();  // all waves done reading K before P overwrites it

#pragma unroll
  for (int r = 0; r < 4; ++r) {
    float mx = -3.0e38f;
#pragma unroll
    for (int nt = 0; nt < 16; ++nt) mx = fmaxf(mx, sa[nt][r]);
    mx = fmaxf(mx, __shfl_xor(mx, 1));
    mx = fmaxf(mx, __shfl_xor(mx, 2));
    mx = fmaxf(mx, __shfl_xor(mx, 4));
    mx = fmaxf(mx, __shfl_xor(mx, 8));
    float e[16];
    float sum = 0.f;
#pragma unroll
    for (int nt = 0; nt < 16; ++nt) {
      e[nt] = __expf((sa[nt][r] - mx) * 0.125f);
      sum += e[nt];
    }
    sum += __shfl_xor(sum, 1);
    sum += __shfl_xor(sum, 2);
    sum += __shfl_xor(sum, 4);
    sum += __shfl_xor(sum, 8);
    float rsc = 1.0f / sum;
    int prow = wb + quad * 4 + r;
#pragma unroll
    for (int nt = 0; nt < 16; ++nt) {
      int col = nt * 16 + l16;
      KsPs[prow * 256 + (((col >> 3) ^ (prow & 7)) * 8) + (col & 7)] =
          (short)f2b(e[nt] * rsc);
    }
  }
  __syncthreads();

  f32x4 ya[4];
#pragma unroll
  for (int j = 0; j < 4; ++j)
#pragma unroll
    for (int r = 0; r < 4; ++r) ya[j][r] = 0.f;
  int m = wb + l16;
#pragma unroll
  for (int kk = 0; kk < 8; ++kk) {
    bf16x8 af = *(const bf16x8*)&KsPs[m * 256 + (((kk * 4 + quad) ^ (m & 7)) * 8)];
#pragma unroll
    for (int j = 0; j < 4; ++j) {
      int d = j * 16 + l16;
      bf16x8 bfr = *(const bf16x8*)&Vt[d * 256 + (((kk * 4 + quad) ^ (d & 7)) * 8)];
      ya[j] = __builtin_amdgcn_mfma_f32_16x16x32_bf16(af, bfr, ya[j], 0, 0, 0);
    }
  }
#pragma unroll
  for (int j = 0; j < 4; ++j)
#pragma unroll
    for (int r = 0; r < 4; ++r)
      Y[((size_t)(b * 4096 + t0 + wb + quad * 4 + r)) * 1024 + h * 64 + j * 16 + l16] =
          f2b(ya[j][r]);
}

// ---------------------------------------------------------------------------
extern "C" void kernel_launch(void* const* d_in, const int* in_sizes, int n_in,
                              void* d_out, int out_size, void* d_ws, size_t ws_size,
                              hipStream_t stream) {
  const float* x       = (const float*)d_in[0];
  const float* xf      = (const float*)d_in[1];
  const float* emb     = (const float*)d_in[2];
  const float* norm_g  = (const float*)d_in[3];
  const float* norm_b  = (const float*)d_in[4];
  const float* tnorm_g = (const float*)d_in[5];
  const float* tnorm_b = (const float*)d_in[6];
  const float* Wq      = (const float*)d_in[7];
  const float* bq      = (const float*)d_in[8];
  const float* Wk      = (const float*)d_in[9];
  const float* bk      = (const float*)d_in[10];
  const float* Wv      = (const float*)d_in[11];
  const float* bv      = (const float*)d_in[12];
  const float* We      = (const float*)d_in[13];
  const float* be      = (const float*)d_in[14];
  const float* snorm_g = (const float*)d_in[15];
  const float* snorm_b = (const float*)d_in[16];
  const float* Wo      = (const float*)d_in[17];
  const float* bo      = (const float*)d_in[18];

  const size_t MB = 1024 * 1024;
  // d_out (64 MB f32) hosts transient bf16 buffers that die before the final
  // full-d_out write: Q (32 MB) + Wq^T/Wk^T/Wv^T transposed weights.
  char* dout = (char*)d_out;
  u16* qbuf = (u16*)(dout);             // 32 MB bf16 Q (dead after attn)
  u16* wqt  = (u16*)(dout + 32 * MB);   // 2 MB   (dead after Q-GEMM)
  u16* wkt  = (u16*)(dout + 34 * MB);   // 1.5 MB (dead after K-GEMM)
  u16* wvt  = (u16*)(dout + 36 * MB);   // 1.5 MB (dead after V-GEMM)
  float* out = (float*)d_out;

  // Workspace: ~39.6 MB total.
  char* ws = (char*)d_ws;
  u16* big1 = (u16*)(ws);                        // 32 MB: LN(x) -> y -> s
  u16* xfn  = (u16*)(ws + 32 * MB);              // 1.5 MB
  u16* kws  = (u16*)(ws + 33 * MB + 512 * 1024); // 2 MB  (B,256,1024)
  u16* vtws = (u16*)(ws + 35 * MB + 512 * 1024); // 2 MB  (B,1024,256)
  u16* wot  = (u16*)(ws + 37 * MB + 512 * 1024); // 2 MB  (needed during final GEMM)
  float* embo = (float*)(ws + 39 * MB + 512 * 1024); // 32 KB f32

  // weight transposes (f32 -> bf16, B-operand wants k-contiguous), one launch
  transpose4_k<<<dim3(32, 32, 4), dim3(32, 8), 0, stream>>>(
      Wq, Wk, Wv, Wo, wqt, wkt, wvt, wot);

  // layernorms (f32 -> bf16)
  ln_k<<<16384, 256, 0, stream>>>(x, norm_g, norm_b, big1, 1024);
  ln_k<<<1024, 256, 0, stream>>>(xf, tnorm_g, tnorm_b, xfn, 768);

  // projections: Q -> d_out (bf16); K -> kws; V -> vtws (transposed store)
  // rows on grid-x for XCD-local A reuse
  gemm_bt_k<<<dim3(128, 8), 256, 0, stream>>>(big1, wqt, bq, nullptr, qbuf, nullptr, 16384, 1024, 1024, 0);
  gemm_bt_k<<<dim3(8, 8), 256, 0, stream>>>(xfn, wkt, bk, nullptr, kws, nullptr, 1024, 1024, 768, 0);
  gemm_bt_k<<<dim3(8, 8), 256, 0, stream>>>(xfn, wvt, bv, nullptr, vtws, nullptr, 1024, 1024, 768, 1);

  // emb -> scale/shift (f32)
  emb_k<<<dim3(8, 4), 256, 0, stream>>>(emb, We, be, embo);

  // attention: reads Q (=d_out lower half), writes y (bf16) -> big1
  attn_k<<<dim3(64, 16, 4), 256, 0, stream>>>(qbuf, kws, vtws, big1);

  // stylization in-place: big1 (y) -> big1 (s)
  style_k<<<16384, 256, 0, stream>>>(big1, snorm_g, snorm_b, embo, big1);

  // out projection + bias + residual(x, f32) -> d_out (f32, full overwrite)
  gemm_bt_k<<<dim3(128, 8), 256, 0, stream>>>(big1, wot, bo, x, nullptr, out, 16384, 1024, 1024, 2);
}